// Round 14
// baseline (445.802 us; speedup 1.0000x reference)
//
#include <hip/hip_runtime.h>
#include <hip/hip_bf16.h>

#define B_   64
#define S_   2048
#define TRG_ 512
#define K_   1024

typedef short short8 __attribute__((ext_vector_type(8)));
typedef float f32x4  __attribute__((ext_vector_type(4)));
typedef unsigned short us4 __attribute__((ext_vector_type(4)));

__device__ __forceinline__ unsigned short f2bf(float f) {
    union { float f; unsigned int u; } v; v.f = f;
    unsigned int u = v.u;
    unsigned int r = (u + 0x7fffu + ((u >> 16) & 1u)) >> 16;  // RNE
    return (unsigned short)r;
}

__device__ __forceinline__ short8 cvt8(f32x4 a, f32x4 b) {
    union { __hip_bfloat162 h[4]; short8 v; } u;
    u.h[0] = __float22bfloat162_rn(float2{a[0], a[1]});
    u.h[1] = __float22bfloat162_rn(float2{a[2], a[3]});
    u.h[2] = __float22bfloat162_rn(float2{b[0], b[1]});
    u.h[3] = __float22bfloat162_rn(float2{b[2], b[3]});
    return u.v;
}

// ---------------- W_en fp32 -> bf16 ----------------
__global__ void wen_convert_kernel(const float* __restrict__ Wen,
                                   unsigned short* __restrict__ Wbf) {
    int idx = blockIdx.x * 256 + threadIdx.x;
    float4 f = ((const float4*)Wen)[idx];
    us4 o = { f2bf(f.x), f2bf(f.y), f2bf(f.z), f2bf(f.w) };
    ((us4*)Wbf)[idx] = o;
}

// ---------------- deproj ----------------
__global__ void deproj_kernel(const float* __restrict__ dehy,
                              const float* __restrict__ Wde,
                              const float* __restrict__ ben,
                              float* __restrict__ dp) {
    int b = blockIdx.x >> 1;
    int h = ((blockIdx.x & 1) << 8) + threadIdx.x;
    const float4* dv = (const float4*)(dehy + (size_t)b * TRG_);
    const float4* wv = (const float4*)(Wde + (size_t)h * TRG_);
    float s = ben[h];
    #pragma unroll 4
    for (int t = 0; t < TRG_ / 4; ++t) {
        float4 a = dv[t], w = wv[t];
        s += a.x * w.x + a.y * w.y + a.z * w.z + a.w * w.w;
    }
    dp[b * TRG_ + h] = s;
}

// ---------------- fused score GEMM (m97-mirror, h-partial) ----------------
// Tile 128(M) x 128(N h-slice) x 32(K). 256 thr = 4 waves (2m x 2n), wave-tile
// 64x64 = 4x4 frags, acc 64 VGPR. LDS 33 KB -> 4 blocks/CU (m97 regime:
// cross-block co-scheduling overlaps HBM/L2/LDS/MFMA pipes). 4096 blocks =
// 1024 m-panels x 4 h-slices (slice varies fastest -> siblings concurrent ->
// A-lines shared via L2/L3). Each block writes partial ee over its h-slice;
// softmax kernel sums slices + masks. Proven race-free R9 2-phase loop.
__global__ __launch_bounds__(256, 4) void score_kernel(
    const float* __restrict__ enhy,
    const unsigned short* __restrict__ Wbf,
    const float* __restrict__ dp,
    const float* __restrict__ past_attn,
    const float* __restrict__ w_cv,
    const float* __restrict__ w_warp,
    float* __restrict__ part_ee)
{
    __shared__ unsigned short Abuf[2][128 * 32];   // 16 KB
    __shared__ unsigned short Bbuf[2][128 * 32];   // 16 KB
    __shared__ float red[2][128];                  // 1 KB

    const int tid  = threadIdx.x;
    const int lane = tid & 63;
    const int w    = tid >> 6;       // 0..3
    const int wm   = w >> 1;         // 0..1 (m-half)
    const int wn   = w & 1;          // 0..1 (n-half)
    const int lj   = lane & 15;
    const int lg   = lane >> 4;
    const int p    = blockIdx.x >> 2;
    const int sl   = blockIdx.x & 3;     // h-slice
    const int m0   = p << 7;             // flat row into [B*S]
    const int h0   = sl << 7;
    const int b    = m0 >> 11;

    // fragment-read 16B-chunk swizzle: chunk = lg ^ ((row>>1)&3); frag bases
    // are multiples of 16 so (row>>1)&3 == (lj>>1)&3 for all frags.
    const int kx = ((lg ^ ((lj >> 1) & 3)) << 4);

    f32x4 acc[4][4];
    const f32x4 fz = {0.f, 0.f, 0.f, 0.f};
    #pragma unroll
    for (int i = 0; i < 4; ++i)
        #pragma unroll
        for (int j = 0; j < 4; ++j) acc[i][j] = fz;

    // A staging: row = tid>>1 (128 rows), k-half ah = tid&1 (16 floats each)
    const int arow = tid >> 1;
    const int ah   = tid & 1;
    const float* aSrc = enhy + (size_t)(m0 + arow) * K_ + (ah << 4);
    const int asw = (arow >> 1) & 3;
    const int aD0 = arow * 64 + ((((ah << 1) | 0) ^ asw) << 4);
    const int aD1 = arow * 64 + ((((ah << 1) | 1) ^ asw) << 4);

    // B staging (gload_lds, 2 instrs/wave): cp = j*256+tid; brow = j*64+(tid>>2),
    // src chunk = (tid&3) ^ ((tid>>3)&3)  [(brow>>1)&3 == (tid>>3)&3]
    const unsigned short* bSrc0 = Wbf + (size_t)(h0 + (tid >> 2)) * K_
                                + ((size_t)((tid & 3) ^ ((tid >> 3) & 3)) << 3);
    const int bDst0 = (tid >> 6) << 10;   // w*1024; instr j adds j*4096

#define LOADA(R0, R1, R2, R3, kt) { \
    const float* p_ = aSrc + ((kt) << 5); \
    R0 = *(const f32x4*)p_;       R1 = *(const f32x4*)(p_ + 4); \
    R2 = *(const f32x4*)(p_ + 8); R3 = *(const f32x4*)(p_ + 12); }
#define WRITEA(sel, R0, R1, R2, R3) { \
    *(short8*)((char*)&Abuf[0][0] + (sel) * 8192 + aD0) = cvt8(R0, R1); \
    *(short8*)((char*)&Abuf[0][0] + (sel) * 8192 + aD1) = cvt8(R2, R3); }
#define STAGEB(sel, kt) { \
    _Pragma("unroll") \
    for (int j_ = 0; j_ < 2; ++j_) { \
        __builtin_amdgcn_global_load_lds( \
            (const __attribute__((address_space(1))) void*)(bSrc0 + (size_t)j_ * 64 * K_ + ((kt) << 5)), \
            (__attribute__((address_space(3))) void*)((char*)&Bbuf[0][0] + (sel) * 8192 + j_ * 4096 + bDst0), \
            16, 0, 0); \
    } }

    auto compute = [&](int sel) {
        const char* Bbase = (const char*)&Bbuf[0][0] + sel * 8192;
        const char* Abase = (const char*)&Abuf[0][0] + sel * 8192;
        short8 bfr[4];
        #pragma unroll
        for (int fn = 0; fn < 4; ++fn) {
            int r = (wn << 6) + (fn << 4) + lj;
            bfr[fn] = *(const short8*)(Bbase + r * 64 + kx);
        }
        #pragma unroll
        for (int fm = 0; fm < 4; ++fm) {
            int rA = (wm << 6) + (fm << 4) + lj;
            short8 af = *(const short8*)(Abase + rA * 64 + kx);
            #pragma unroll
            for (int fn = 0; fn < 4; ++fn)
                acc[fm][fn] = __builtin_amdgcn_mfma_f32_16x16x32_bf16(af, bfr[fn], acc[fm][fn], 0, 0, 0);
        }
    };

    // ---- prologue: tile 0 fully staged ----
    f32x4 a0, a1, a2, a3;
    LOADA(a0, a1, a2, a3, 0);
    STAGEB(0, 0);
    WRITEA(0, a0, a1, a2, a3);
    __syncthreads();

    // ---- main loop: 2-phase, stage(kt+1) || compute(kt), one barrier/step ----
    #pragma unroll 2
    for (int kt = 0; kt < 32; ++kt) {
        const int cur = kt & 1, nxt = cur ^ 1;
        if (kt < 31) {
            STAGEB(nxt, kt + 1);
            LOADA(a0, a1, a2, a3, kt + 1);
        }
        compute(cur);
        if (kt < 31) WRITEA(nxt, a0, a1, a2, a3);
        __syncthreads();
    }

#undef LOADA
#undef WRITEA
#undef STAGEB

    // ---- epilogue: v = acc + dep + pa*wcv; tanh; *w_warp; h-slice partial ----
    float dep4[4], wcv4[4], wwp4[4];
    #pragma unroll
    for (int fn = 0; fn < 4; ++fn) {
        int h = h0 + (wn << 6) + (fn << 4) + lj;
        dep4[fn] = dp[b * TRG_ + h];
        wcv4[fn] = w_cv[h];
        wwp4[fn] = w_warp[h];
    }
    #pragma unroll
    for (int fm = 0; fm < 4; ++fm) {
        #pragma unroll
        for (int reg = 0; reg < 4; ++reg) {
            int row = (wm << 6) + (fm << 4) + (lg << 2) + reg;   // 0..127
            float pa = past_attn[m0 + row];
            float pp = 0.f;
            #pragma unroll
            for (int fn = 0; fn < 4; ++fn) {
                float v = acc[fm][fn][reg] + dep4[fn] + pa * wcv4[fn];
                float e = __expf(2.f * v);                       // tanh = 1 - 2/(e^{2v}+1)
                float t = 1.f - 2.f * __builtin_amdgcn_rcpf(e + 1.f);
                pp += t * wwp4[fn];
            }
            pp += __shfl_xor(pp, 1);
            pp += __shfl_xor(pp, 2);
            pp += __shfl_xor(pp, 4);
            pp += __shfl_xor(pp, 8);
            if (lj == 0) red[wn][row] = pp;
        }
    }
    __syncthreads();
    if (tid < 128)
        part_ee[(size_t)sl * (B_ * S_) + m0 + tid] = red[0][tid] + red[1][tid];
}

// ---------------- sum slices + mask + softmax over S per batch row ----------------
__global__ void softmax_kernel(const float* __restrict__ part_ee,
                               const int* __restrict__ src_mask,
                               float* __restrict__ out_ee,
                               float* __restrict__ attn) {
    int b = blockIdx.x, tid = threadIdx.x;       // 256 threads
    float v[8]; float mx = -3.0e38f;
    #pragma unroll
    for (int i = 0; i < 8; ++i) {
        int off = b * S_ + tid + (i << 8);
        float e = part_ee[off] + part_ee[131072 + off]
                + part_ee[262144 + off] + part_ee[393216 + off];
        if (src_mask[off] == 0) e = -1e20f;
        out_ee[off] = e;
        v[i] = e; mx = fmaxf(mx, e);
    }
    #pragma unroll
    for (int off = 32; off > 0; off >>= 1) mx = fmaxf(mx, __shfl_xor(mx, off));
    __shared__ float sred[4];
    int w = tid >> 6, lane = tid & 63;
    if (lane == 0) sred[w] = mx;
    __syncthreads();
    mx = fmaxf(fmaxf(sred[0], sred[1]), fmaxf(sred[2], sred[3]));
    float sum = 0.f;
    #pragma unroll
    for (int i = 0; i < 8; ++i) { v[i] = __expf(v[i] - mx); sum += v[i]; }
    #pragma unroll
    for (int off = 32; off > 0; off >>= 1) sum += __shfl_xor(sum, off);
    __syncthreads();
    if (lane == 0) sred[w] = sum;
    __syncthreads();
    sum = sred[0] + sred[1] + sred[2] + sred[3];
    float inv = 1.f / sum;
    float* orow = attn + (size_t)b * S_;
    #pragma unroll
    for (int i = 0; i < 8; ++i) orow[tid + (i << 8)] = v[i] * inv;
}

// ---------------- context ----------------
__global__ void ctx_partial_kernel(const float* __restrict__ attn,
                                   const float* __restrict__ enhy,
                                   float* __restrict__ part) {
    int bx = blockIdx.x;
    int b = bx >> 5, sc = bx & 31;
    int tid = threadIdx.x;
    const float4* e4 = (const float4*)(enhy + ((size_t)b * S_ + sc * 64) * K_);
    const float* ar = attn + (size_t)b * S_ + sc * 64;
    float4 acc = {0.f, 0.f, 0.f, 0.f};
    #pragma unroll 8
    for (int s = 0; s < 64; ++s) {
        float a = ar[s];
        float4 ev = e4[(size_t)s * 256 + tid];
        acc.x += a * ev.x; acc.y += a * ev.y; acc.z += a * ev.z; acc.w += a * ev.w;
    }
    ((float4*)part)[(size_t)(sc * 64 + b) * 256 + tid] = acc;
}

__global__ void ctx_reduce_kernel(const float* __restrict__ part, float* __restrict__ outc) {
    int idx = blockIdx.x * 256 + threadIdx.x;
    int b = idx >> 10, d = idx & 1023;
    float s = 0.f;
    #pragma unroll
    for (int sc = 0; sc < 32; ++sc) s += part[(size_t)((sc << 6) + b) * 1024 + d];
    outc[idx] = s;
}

extern "C" void kernel_launch(void* const* d_in, const int* in_sizes, int n_in,
                              void* d_out, int out_size, void* d_ws, size_t ws_size,
                              hipStream_t stream) {
    (void)in_sizes; (void)n_in; (void)out_size; (void)ws_size;

    const float* dehy = (const float*)d_in[0];
    const float* enhy = (const float*)d_in[1];
    const float* past = (const float*)d_in[2];
    const int*   mask = (const int*)d_in[3];
    const float* Wen  = (const float*)d_in[4];
    const float* ben  = (const float*)d_in[5];
    const float* Wde  = (const float*)d_in[6];
    const float* wcv  = (const float*)d_in[7];
    const float* wwp  = (const float*)d_in[8];

    float* out      = (float*)d_out;
    float* out_c    = out;                      // 64*1024
    float* out_attn = out + 65536;              // 64*2048
    float* out_ee   = out + 65536 + 131072;     // 64*2048

    char* ws = (char*)d_ws;
    unsigned short* Wbf  = (unsigned short*)ws;               // 1 MB
    float* dp      = (float*)(ws + (1 << 20));                // 128 KB
    float* part    = (float*)(ws + (1 << 20) + (1 << 17));    // 8 MB
    float* part_ee = (float*)(ws + (size_t)10 * (1 << 20));   // 2 MB (4 x 131072 f32)

    wen_convert_kernel<<<512, 256, 0, stream>>>(Wen, Wbf);
    deproj_kernel<<<128, 256, 0, stream>>>(dehy, Wde, ben, dp);
    score_kernel<<<4096, 256, 0, stream>>>(enhy, Wbf, dp, past, wcv, wwp, part_ee);
    softmax_kernel<<<64, 256, 0, stream>>>(part_ee, mask, out_ee, out_attn);
    ctx_partial_kernel<<<2048, 256, 0, stream>>>(out_attn, enhy, part);
    ctx_reduce_kernel<<<256, 256, 0, stream>>>(part, out_c);
}

// Round 15
// 389.460 us; speedup vs baseline: 1.1447x; 1.1447x over previous
//
#include <hip/hip_runtime.h>
#include <hip/hip_bf16.h>

#define B_   64
#define S_   2048
#define TRG_ 512
#define K_   1024

typedef short short8 __attribute__((ext_vector_type(8)));
typedef short short4v __attribute__((ext_vector_type(4)));
typedef float f32x4  __attribute__((ext_vector_type(4)));
typedef unsigned short us4 __attribute__((ext_vector_type(4)));

__device__ __forceinline__ unsigned short f2bf(float f) {
    union { float f; unsigned int u; } v; v.f = f;
    unsigned int u = v.u;
    unsigned int r = (u + 0x7fffu + ((u >> 16) & 1u)) >> 16;  // RNE
    return (unsigned short)r;
}

__device__ __forceinline__ short4v cvt4(f32x4 a) {
    union { __hip_bfloat162 h[2]; short4v v; } u;
    u.h[0] = __float22bfloat162_rn(float2{a[0], a[1]});
    u.h[1] = __float22bfloat162_rn(float2{a[2], a[3]});
    return u.v;
}

// ---------------- W_en fp32 -> bf16 ----------------
__global__ void wen_convert_kernel(const float* __restrict__ Wen,
                                   unsigned short* __restrict__ Wbf) {
    int idx = blockIdx.x * 256 + threadIdx.x;
    float4 f = ((const float4*)Wen)[idx];
    us4 o = { f2bf(f.x), f2bf(f.y), f2bf(f.z), f2bf(f.w) };
    ((us4*)Wbf)[idx] = o;
}

// ---------------- deproj ----------------
__global__ void deproj_kernel(const float* __restrict__ dehy,
                              const float* __restrict__ Wde,
                              const float* __restrict__ ben,
                              float* __restrict__ dp) {
    int b = blockIdx.x >> 1;
    int h = ((blockIdx.x & 1) << 8) + threadIdx.x;
    const float4* dv = (const float4*)(dehy + (size_t)b * TRG_);
    const float4* wv = (const float4*)(Wde + (size_t)h * TRG_);
    float s = ben[h];
    #pragma unroll 4
    for (int t = 0; t < TRG_ / 4; ++t) {
        float4 a = dv[t], w = wv[t];
        s += a.x * w.x + a.y * w.y + a.z * w.z + a.w * w.w;
    }
    dp[b * TRG_ + h] = s;
}

// ---------------- fused score GEMM + tanh + w_warp reduce + mask ----------------
// R9 (best measured: total 377 us, absmax 0.0039): tile 64(M) x 512(N) x 32(K),
// 8 waves 1m x 8n, acc 4x4, LDS 74 KB -> 2 blocks/CU, non-temporal A stream.
// Session verdict: 8 structural variants (occupancy 1-4 blk/CU, prefetch 0-3,
// counted/drain vmcnt, phase interleave, K-rotation, h-partials) all land
// ~300-350 us for this kernel -> latency-serialization-pinned for this shape
// (~460 TF effective, above the m97-structure shape curve for K-loop depth 32).
__global__ __launch_bounds__(512, 4) void score_kernel(
    const float* __restrict__ enhy,
    const unsigned short* __restrict__ Wbf,
    const float* __restrict__ dp,
    const float* __restrict__ past_attn,
    const int* __restrict__ src_mask,
    const float* __restrict__ w_cv,
    const float* __restrict__ w_warp,
    float* __restrict__ out_ee)
{
    __shared__ unsigned short Bbuf[2][512 * 32];   // 64 KB
    __shared__ unsigned short Abuf[2][64 * 32];    // 8 KB
    __shared__ float red[8][64];                   // 2 KB

    const int tid  = threadIdx.x;
    const int lane = tid & 63;
    const int w    = tid >> 6;       // 0..7 (n-slice)
    const int lj   = lane & 15;
    const int lg   = lane >> 4;
    const int m0   = blockIdx.x * 64;    // flat row into [B*S]
    const int b    = m0 >> 11;

    const int kx = ((lg ^ ((lj >> 1) & 3)) << 4);

    f32x4 acc[4][4];
    const f32x4 fz = {0.f, 0.f, 0.f, 0.f};
    #pragma unroll
    for (int i = 0; i < 4; ++i)
        #pragma unroll
        for (int j = 0; j < 4; ++j) acc[i][j] = fz;

    const int arow = tid >> 3;
    const int akq  = tid & 7;
    const float* aSrc = enhy + (size_t)(m0 + arow) * K_ + (akq << 2);
    const int aDstByte = arow * 64 + (((akq >> 1) ^ ((arow >> 1) & 3)) << 4) + ((akq & 1) << 3);

    const int brow0 = tid >> 2;
    const int bkc0  = tid & 3;
    const unsigned short* bSrc0 = Wbf + (size_t)brow0 * K_ + ((bkc0 ^ ((brow0 >> 1) & 3)) << 3);
    const int bDst0 = w * 1024;

#define LOADA(R, kt) { R = __builtin_nontemporal_load((const f32x4*)(aSrc + ((kt) << 5))); }
#define WRITEA(sel, R) { \
    *(short4v*)((char*)&Abuf[0][0] + (sel) * 4096 + aDstByte) = cvt4(R); }
#define STAGEB(sel, kt) { \
    _Pragma("unroll") \
    for (int j_ = 0; j_ < 4; ++j_) { \
        __builtin_amdgcn_global_load_lds( \
            (const __attribute__((address_space(1))) void*)(bSrc0 + (size_t)j_ * 128 * K_ + ((kt) << 5)), \
            (__attribute__((address_space(3))) void*)((char*)&Bbuf[0][0] + (sel) * 32768 + bDst0 + j_ * 8192), \
            16, 0, 0); \
    } }

    auto compute = [&](int sel) {
        const char* Bbase = (const char*)&Bbuf[0][0] + sel * 32768;
        const char* Abase = (const char*)&Abuf[0][0] + sel * 4096;
        short8 bfr[4];
        #pragma unroll
        for (int fn = 0; fn < 4; ++fn) {
            int r = (w << 6) + (fn << 4) + lj;
            bfr[fn] = *(const short8*)(Bbase + r * 64 + kx);
        }
        #pragma unroll
        for (int fm = 0; fm < 4; ++fm) {
            int rA = (fm << 4) + lj;
            short8 af = *(const short8*)(Abase + rA * 64 + kx);
            #pragma unroll
            for (int fn = 0; fn < 4; ++fn)
                acc[fm][fn] = __builtin_amdgcn_mfma_f32_16x16x32_bf16(af, bfr[fn], acc[fm][fn], 0, 0, 0);
        }
    };

    // ---- prologue: tile 0 fully staged ----
    f32x4 a_c, a_n;
    LOADA(a_c, 0);
    STAGEB(0, 0);
    WRITEA(0, a_c);
    __syncthreads();

    // ---- main loop: 2-phase, stage(kt+1) || compute(kt), one barrier/step ----
    #pragma unroll 2
    for (int kt = 0; kt < 32; ++kt) {
        const int cur = kt & 1, nxt = cur ^ 1;
        if (kt < 31) {
            STAGEB(nxt, kt + 1);
            LOADA(a_n, kt + 1);
        }
        compute(cur);
        if (kt < 31) WRITEA(nxt, a_n);
        __syncthreads();
    }

#undef LOADA
#undef WRITEA
#undef STAGEB

    // ---- epilogue: v = acc + dep + pa*wcv; tanh; *w_warp; reduce over h ----
    float dep4[4], wcv4[4], wwp4[4];
    #pragma unroll
    for (int fn = 0; fn < 4; ++fn) {
        int h = (w << 6) + (fn << 4) + lj;
        dep4[fn] = dp[b * TRG_ + h];
        wcv4[fn] = w_cv[h];
        wwp4[fn] = w_warp[h];
    }
    #pragma unroll
    for (int fm = 0; fm < 4; ++fm) {
        #pragma unroll
        for (int reg = 0; reg < 4; ++reg) {
            int row = (fm << 4) + (lg << 2) + reg;       // 0..63
            float pa = past_attn[m0 + row];
            float p = 0.f;
            #pragma unroll
            for (int fn = 0; fn < 4; ++fn) {
                float v = acc[fm][fn][reg] + dep4[fn] + pa * wcv4[fn];
                float e = __expf(2.f * v);                       // tanh = 1 - 2/(e^{2v}+1)
                float t = 1.f - 2.f * __builtin_amdgcn_rcpf(e + 1.f);
                p += t * wwp4[fn];
            }
            p += __shfl_xor(p, 1);
            p += __shfl_xor(p, 2);
            p += __shfl_xor(p, 4);
            p += __shfl_xor(p, 8);
            if (lj == 0) red[w][row] = p;
        }
    }
    __syncthreads();
    if (tid < 64) {
        float ee = 0.f;
        #pragma unroll
        for (int ww = 0; ww < 8; ++ww) ee += red[ww][tid];
        int msk = src_mask[m0 + tid];
        if (msk == 0) ee = -1e20f;
        out_ee[m0 + tid] = ee;
    }
}

// ---------------- softmax over S per batch row ----------------
__global__ void softmax_kernel(const float* __restrict__ ee, float* __restrict__ attn) {
    int b = blockIdx.x, tid = threadIdx.x;
    const float* row = ee + (size_t)b * S_;
    float v[8]; float mx = -3.0e38f;
    #pragma unroll
    for (int i = 0; i < 8; ++i) { v[i] = row[tid + (i << 8)]; mx = fmaxf(mx, v[i]); }
    #pragma unroll
    for (int off = 32; off > 0; off >>= 1) mx = fmaxf(mx, __shfl_xor(mx, off));
    __shared__ float sred[4];
    int w = tid >> 6, lane = tid & 63;
    if (lane == 0) sred[w] = mx;
    __syncthreads();
    mx = fmaxf(fmaxf(sred[0], sred[1]), fmaxf(sred[2], sred[3]));
    float sum = 0.f;
    #pragma unroll
    for (int i = 0; i < 8; ++i) { v[i] = __expf(v[i] - mx); sum += v[i]; }
    #pragma unroll
    for (int off = 32; off > 0; off >>= 1) sum += __shfl_xor(sum, off);
    __syncthreads();
    if (lane == 0) sred[w] = sum;
    __syncthreads();
    sum = sred[0] + sred[1] + sred[2] + sred[3];
    float inv = 1.f / sum;
    float* orow = attn + (size_t)b * S_;
    #pragma unroll
    for (int i = 0; i < 8; ++i) orow[tid + (i << 8)] = v[i] * inv;
}

// ---------------- context: partial over s-chunks (deterministic) ----------------
// ONE change vs R9: the 512 MB enhy stream is non-temporal (zero reuse here);
// keeps attn/part/out L2-resident.
__global__ void ctx_partial_kernel(const float* __restrict__ attn,
                                   const float* __restrict__ enhy,
                                   float* __restrict__ part) {
    int bx = blockIdx.x;
    int b = bx >> 5, sc = bx & 31;
    int tid = threadIdx.x;
    const f32x4* e4 = (const f32x4*)(enhy + ((size_t)b * S_ + sc * 64) * K_);
    const float* ar = attn + (size_t)b * S_ + sc * 64;
    f32x4 acc = {0.f, 0.f, 0.f, 0.f};
    #pragma unroll 8
    for (int s = 0; s < 64; ++s) {
        float a = ar[s];
        f32x4 ev = __builtin_nontemporal_load(&e4[(size_t)s * 256 + tid]);
        acc[0] += a * ev[0]; acc[1] += a * ev[1];
        acc[2] += a * ev[2]; acc[3] += a * ev[3];
    }
    ((f32x4*)part)[(size_t)(sc * 64 + b) * 256 + tid] = acc;
}

__global__ void ctx_reduce_kernel(const float* __restrict__ part, float* __restrict__ outc) {
    int idx = blockIdx.x * 256 + threadIdx.x;
    int b = idx >> 10, d = idx & 1023;
    float s = 0.f;
    #pragma unroll
    for (int sc = 0; sc < 32; ++sc) s += part[(size_t)((sc << 6) + b) * 1024 + d];
    outc[idx] = s;
}

extern "C" void kernel_launch(void* const* d_in, const int* in_sizes, int n_in,
                              void* d_out, int out_size, void* d_ws, size_t ws_size,
                              hipStream_t stream) {
    (void)in_sizes; (void)n_in; (void)out_size; (void)ws_size;

    const float* dehy = (const float*)d_in[0];
    const float* enhy = (const float*)d_in[1];
    const float* past = (const float*)d_in[2];
    const int*   mask = (const int*)d_in[3];
    const float* Wen  = (const float*)d_in[4];
    const float* ben  = (const float*)d_in[5];
    const float* Wde  = (const float*)d_in[6];
    const float* wcv  = (const float*)d_in[7];
    const float* wwp  = (const float*)d_in[8];

    float* out      = (float*)d_out;
    float* out_c    = out;                      // 64*1024
    float* out_attn = out + 65536;              // 64*2048
    float* out_ee   = out + 65536 + 131072;     // 64*2048

    char* ws = (char*)d_ws;
    unsigned short* Wbf = (unsigned short*)ws;              // 1 MB
    float* dp   = (float*)(ws + (1 << 20));                 // 128 KB
    float* part = (float*)(ws + (1 << 20) + (1 << 17));     // 8 MB

    wen_convert_kernel<<<512, 256, 0, stream>>>(Wen, Wbf);
    deproj_kernel<<<128, 256, 0, stream>>>(dehy, Wde, ben, dp);
    score_kernel<<<2048, 512, 0, stream>>>(enhy, Wbf, dp, past, mask, wcv, wwp, out_ee);
    softmax_kernel<<<64, 256, 0, stream>>>(out_ee, out_attn);
    ctx_partial_kernel<<<2048, 256, 0, stream>>>(out_attn, enhy, part);
    ctx_reduce_kernel<<<256, 256, 0, stream>>>(part, out_c);
}

// Round 16
// 339.709 us; speedup vs baseline: 1.3123x; 1.1465x over previous
//
#include <hip/hip_runtime.h>
#include <hip/hip_bf16.h>

#define B_   64
#define S_   2048
#define TRG_ 512
#define K_   1024

typedef short short8 __attribute__((ext_vector_type(8)));
typedef short short4v __attribute__((ext_vector_type(4)));
typedef float f32x4  __attribute__((ext_vector_type(4)));
typedef unsigned short us4 __attribute__((ext_vector_type(4)));

__device__ __forceinline__ unsigned short f2bf(float f) {
    union { float f; unsigned int u; } v; v.f = f;
    unsigned int u = v.u;
    unsigned int r = (u + 0x7fffu + ((u >> 16) & 1u)) >> 16;  // RNE
    return (unsigned short)r;
}

__device__ __forceinline__ short4v cvt4(f32x4 a) {
    union { __hip_bfloat162 h[2]; short4v v; } u;
    u.h[0] = __float22bfloat162_rn(float2{a[0], a[1]});
    u.h[1] = __float22bfloat162_rn(float2{a[2], a[3]});
    return u.v;
}

// ---------------- W_en fp32 -> bf16 ----------------
__global__ void wen_convert_kernel(const float* __restrict__ Wen,
                                   unsigned short* __restrict__ Wbf) {
    int idx = blockIdx.x * 256 + threadIdx.x;
    float4 f = ((const float4*)Wen)[idx];
    us4 o = { f2bf(f.x), f2bf(f.y), f2bf(f.z), f2bf(f.w) };
    ((us4*)Wbf)[idx] = o;
}

// ---------------- deproj ----------------
__global__ void deproj_kernel(const float* __restrict__ dehy,
                              const float* __restrict__ Wde,
                              const float* __restrict__ ben,
                              float* __restrict__ dp) {
    int b = blockIdx.x >> 1;
    int h = ((blockIdx.x & 1) << 8) + threadIdx.x;
    const float4* dv = (const float4*)(dehy + (size_t)b * TRG_);
    const float4* wv = (const float4*)(Wde + (size_t)h * TRG_);
    float s = ben[h];
    #pragma unroll 4
    for (int t = 0; t < TRG_ / 4; ++t) {
        float4 a = dv[t], w = wv[t];
        s += a.x * w.x + a.y * w.y + a.z * w.z + a.w * w.w;
    }
    dp[b * TRG_ + h] = s;
}

// ---------------- fused score GEMM + tanh + w_warp reduce + mask ----------------
// R11 structure, race-pinned. Tile 64(M) x 512(N) x 32(K), 8 waves 1m x 8n,
// acc 4x4 (VGPR ~64). B SINGLE-buffered (32 KB) -> LDS 42 KB -> 3 blocks/CU.
// Per step: STAGEB | SB0 | WRITEA(A kt+1) | SB0 | nt-LOADA(kt+2) | SB0 |
// vmcnt(1)+lgkm(0)+barrier | compute | lgkm(0)+barrier. sched_barrier(0) pins
// issue order so vmcnt(1) provably leaves ONLY the A-load flying (R11's race).
__global__ __launch_bounds__(512, 4) void score_kernel(
    const float* __restrict__ enhy,
    const unsigned short* __restrict__ Wbf,
    const float* __restrict__ dp,
    const float* __restrict__ past_attn,
    const int* __restrict__ src_mask,
    const float* __restrict__ w_cv,
    const float* __restrict__ w_warp,
    float* __restrict__ out_ee)
{
    __shared__ unsigned short Bbuf[512 * 32];      // 32 KB (single buffer)
    __shared__ unsigned short Abuf[2][64 * 32];    // 8 KB
    __shared__ float red[8][64];                   // 2 KB

    const int tid  = threadIdx.x;
    const int lane = tid & 63;
    const int w    = tid >> 6;       // 0..7 (n-slice)
    const int lj   = lane & 15;
    const int lg   = lane >> 4;
    const int m0   = blockIdx.x * 64;    // flat row into [B*S]
    const int b    = m0 >> 11;

    const int kx = ((lg ^ ((lj >> 1) & 3)) << 4);

    f32x4 acc[4][4];
    const f32x4 fz = {0.f, 0.f, 0.f, 0.f};
    #pragma unroll
    for (int i = 0; i < 4; ++i)
        #pragma unroll
        for (int j = 0; j < 4; ++j) acc[i][j] = fz;

    const int arow = tid >> 3;
    const int akq  = tid & 7;
    const float* aSrc = enhy + (size_t)(m0 + arow) * K_ + (akq << 2);
    const int aDstByte = arow * 64 + (((akq >> 1) ^ ((arow >> 1) & 3)) << 4) + ((akq & 1) << 3);

    const int brow0 = tid >> 2;
    const int bkc0  = tid & 3;
    const unsigned short* bSrc0 = Wbf + (size_t)brow0 * K_ + ((bkc0 ^ ((brow0 >> 1) & 3)) << 3);
    const int bDst0 = w * 1024;

#define SB0() __builtin_amdgcn_sched_barrier(0);
#define LOADA(R, kt) { R = __builtin_nontemporal_load((const f32x4*)(aSrc + ((kt) << 5))); }
#define WRITEA(sel, R) { \
    *(short4v*)((char*)&Abuf[0][0] + (sel) * 4096 + aDstByte) = cvt4(R); }
#define STAGEB(kt) { \
    _Pragma("unroll") \
    for (int j_ = 0; j_ < 4; ++j_) { \
        __builtin_amdgcn_global_load_lds( \
            (const __attribute__((address_space(1))) void*)(bSrc0 + (size_t)j_ * 128 * K_ + ((kt) << 5)), \
            (__attribute__((address_space(3))) void*)((char*)&Bbuf[0] + bDst0 + j_ * 8192), \
            16, 0, 0); \
    } }
#define MIDBAR(N) \
    asm volatile("s_waitcnt vmcnt(" #N ") lgkmcnt(0)" ::: "memory"); \
    SB0() __builtin_amdgcn_s_barrier(); SB0()
#define ENDBAR() \
    asm volatile("s_waitcnt lgkmcnt(0)" ::: "memory"); \
    SB0() __builtin_amdgcn_s_barrier(); SB0()

    auto compute = [&](int sel) {
        const char* Bbase = (const char*)&Bbuf[0];
        const char* Abase = (const char*)&Abuf[0][0] + sel * 4096;
        short8 bfr[4];
        #pragma unroll
        for (int fn = 0; fn < 4; ++fn) {
            int r = (w << 6) + (fn << 4) + lj;
            bfr[fn] = *(const short8*)(Bbase + r * 64 + kx);
        }
        #pragma unroll
        for (int fm = 0; fm < 4; ++fm) {
            int rA = (fm << 4) + lj;
            short8 af = *(const short8*)(Abase + rA * 64 + kx);
            #pragma unroll
            for (int fn = 0; fn < 4; ++fn)
                acc[fm][fn] = __builtin_amdgcn_mfma_f32_16x16x32_bf16(af, bfr[fn], acc[fm][fn], 0, 0, 0);
        }
    };

    // ---- prologue: A(0),A(1) in regs; A(0) -> Abuf[0] ----
    f32x4 aR0, aR1;
    LOADA(aR0, 0);
    LOADA(aR1, 1);
    WRITEA(0, aR0);                 // auto-waits A(0)
    SB0()

    // ---- main loop: kt = 0..29 (unrolled x2 for static reg parity) ----
    for (int kt2 = 0; kt2 < 30; kt2 += 2) {
        // kt even: compute Abuf[0]; write A(kt+1)->Abuf[1]; load A(kt+2)->aR0
        STAGEB(kt2) SB0()
        WRITEA(1, aR1); SB0()       // auto-wait drains A(kt+1) load only
        LOADA(aR0, kt2 + 2); SB0()  // issued LAST -> the 1 left flying
        MIDBAR(1)
        compute(0);
        ENDBAR()
        // kt odd
        STAGEB(kt2 + 1) SB0()
        WRITEA(0, aR0); SB0()
        LOADA(aR1, kt2 + 3); SB0()
        MIDBAR(1)
        compute(1);
        ENDBAR()
    }
    // kt = 30
    STAGEB(30) SB0()
    WRITEA(1, aR1); SB0()           // A(31)
    MIDBAR(0)
    compute(0);
    ENDBAR()
    // kt = 31
    STAGEB(31) SB0()
    MIDBAR(0)
    compute(1);

#undef SB0
#undef LOADA
#undef WRITEA
#undef STAGEB
#undef MIDBAR
#undef ENDBAR

    // ---- epilogue: v = acc + dep + pa*wcv; tanh; *w_warp; reduce over h ----
    float dep4[4], wcv4[4], wwp4[4];
    #pragma unroll
    for (int fn = 0; fn < 4; ++fn) {
        int h = (w << 6) + (fn << 4) + lj;
        dep4[fn] = dp[b * TRG_ + h];
        wcv4[fn] = w_cv[h];
        wwp4[fn] = w_warp[h];
    }
    #pragma unroll
    for (int fm = 0; fm < 4; ++fm) {
        #pragma unroll
        for (int reg = 0; reg < 4; ++reg) {
            int row = (fm << 4) + (lg << 2) + reg;       // 0..63
            float pa = past_attn[m0 + row];
            float p = 0.f;
            #pragma unroll
            for (int fn = 0; fn < 4; ++fn) {
                float v = acc[fm][fn][reg] + dep4[fn] + pa * wcv4[fn];
                float e = __expf(2.f * v);                       // tanh = 1 - 2/(e^{2v}+1)
                float t = 1.f - 2.f * __builtin_amdgcn_rcpf(e + 1.f);
                p += t * wwp4[fn];
            }
            p += __shfl_xor(p, 1);
            p += __shfl_xor(p, 2);
            p += __shfl_xor(p, 4);
            p += __shfl_xor(p, 8);
            if (lj == 0) red[w][row] = p;
        }
    }
    __syncthreads();
    if (tid < 64) {
        float ee = 0.f;
        #pragma unroll
        for (int ww = 0; ww < 8; ++ww) ee += red[ww][tid];
        int msk = src_mask[m0 + tid];
        if (msk == 0) ee = -1e20f;
        out_ee[m0 + tid] = ee;
    }
}

// ---------------- row stats: per-row softmax max + 1/sum ----------------
__global__ void rowstat_kernel(const float* __restrict__ ee, float2* __restrict__ mxinv) {
    int b = blockIdx.x, tid = threadIdx.x;   // 64 blocks x 256 threads
    const float* row = ee + (size_t)b * S_;
    float v[8]; float mx = -3.0e38f;
    #pragma unroll
    for (int i = 0; i < 8; ++i) { v[i] = row[tid + (i << 8)]; mx = fmaxf(mx, v[i]); }
    #pragma unroll
    for (int off = 32; off > 0; off >>= 1) mx = fmaxf(mx, __shfl_xor(mx, off));
    __shared__ float sred[4];
    int w = tid >> 6, lane = tid & 63;
    if (lane == 0) sred[w] = mx;
    __syncthreads();
    mx = fmaxf(fmaxf(sred[0], sred[1]), fmaxf(sred[2], sred[3]));
    float sum = 0.f;
    #pragma unroll
    for (int i = 0; i < 8; ++i) sum += __expf(v[i] - mx);
    #pragma unroll
    for (int off = 32; off > 0; off >>= 1) sum += __shfl_xor(sum, off);
    __syncthreads();
    if (lane == 0) sred[w] = sum;
    __syncthreads();
    sum = sred[0] + sred[1] + sred[2] + sred[3];
    if (tid == 0) mxinv[b] = float2{mx, 1.f / sum};
}

// ---------------- context partial + inline attn compute/write ----------------
__global__ void ctx_partial_kernel(const float* __restrict__ ee,
                                   const float2* __restrict__ mxinv,
                                   const float* __restrict__ enhy,
                                   float* __restrict__ attn,
                                   float* __restrict__ part) {
    __shared__ float a_sh[64];
    int bx = blockIdx.x;
    int b = bx >> 5, sc = bx & 31;
    int tid = threadIdx.x;               // 256
    float2 mi = mxinv[b];
    if (tid < 64) {
        float a = __expf(ee[(size_t)b * S_ + sc * 64 + tid] - mi.x) * mi.y;
        a_sh[tid] = a;
        attn[(size_t)b * S_ + sc * 64 + tid] = a;   // each attn elem written once
    }
    __syncthreads();
    const float4* e4 = (const float4*)(enhy + ((size_t)b * S_ + sc * 64) * K_);
    float4 acc = {0.f, 0.f, 0.f, 0.f};
    #pragma unroll 8
    for (int s = 0; s < 64; ++s) {
        float a = a_sh[s];
        float4 ev = e4[(size_t)s * 256 + tid];
        acc.x += a * ev.x; acc.y += a * ev.y; acc.z += a * ev.z; acc.w += a * ev.w;
    }
    ((float4*)part)[(size_t)(sc * 64 + b) * 256 + tid] = acc;
}

__global__ void ctx_reduce_kernel(const float* __restrict__ part, float* __restrict__ outc) {
    int idx = blockIdx.x * 256 + threadIdx.x;
    int b = idx >> 10, d = idx & 1023;
    float s = 0.f;
    #pragma unroll
    for (int sc = 0; sc < 32; ++sc) s += part[(size_t)((sc << 6) + b) * 1024 + d];
    outc[idx] = s;
}

extern "C" void kernel_launch(void* const* d_in, const int* in_sizes, int n_in,
                              void* d_out, int out_size, void* d_ws, size_t ws_size,
                              hipStream_t stream) {
    (void)in_sizes; (void)n_in; (void)out_size; (void)ws_size;

    const float* dehy = (const float*)d_in[0];
    const float* enhy = (const float*)d_in[1];
    const float* past = (const float*)d_in[2];
    const int*   mask = (const int*)d_in[3];
    const float* Wen  = (const float*)d_in[4];
    const float* ben  = (const float*)d_in[5];
    const float* Wde  = (const float*)d_in[6];
    const float* wcv  = (const float*)d_in[7];
    const float* wwp  = (const float*)d_in[8];

    float* out      = (float*)d_out;
    float* out_c    = out;                      // 64*1024
    float* out_attn = out + 65536;              // 64*2048
    float* out_ee   = out + 65536 + 131072;     // 64*2048

    char* ws = (char*)d_ws;
    unsigned short* Wbf = (unsigned short*)ws;               // 1 MB
    float* dp    = (float*)(ws + (1 << 20));                 // 128 KB
    float* part  = (float*)(ws + (1 << 20) + (1 << 17));     // 8 MB
    float2* mxiv = (float2*)(ws + (size_t)10 * (1 << 20));   // 512 B

    wen_convert_kernel<<<512, 256, 0, stream>>>(Wen, Wbf);
    deproj_kernel<<<128, 256, 0, stream>>>(dehy, Wde, ben, dp);
    score_kernel<<<2048, 512, 0, stream>>>(enhy, Wbf, dp, past, mask, wcv, wwp, out_ee);
    rowstat_kernel<<<64, 256, 0, stream>>>(out_ee, mxiv);
    ctx_partial_kernel<<<2048, 256, 0, stream>>>(out_ee, mxiv, enhy, out_attn, part);
    ctx_reduce_kernel<<<256, 256, 0, stream>>>(part, out_c);
}

// Round 17
// 339.194 us; speedup vs baseline: 1.3143x; 1.0015x over previous
//
#include <hip/hip_runtime.h>
#include <hip/hip_bf16.h>

#define B_   64
#define S_   2048
#define TRG_ 512
#define K_   1024

typedef short short8 __attribute__((ext_vector_type(8)));
typedef short short4v __attribute__((ext_vector_type(4)));
typedef float f32x4  __attribute__((ext_vector_type(4)));
typedef unsigned short us4 __attribute__((ext_vector_type(4)));

__device__ __forceinline__ unsigned short f2bf(float f) {
    union { float f; unsigned int u; } v; v.f = f;
    unsigned int u = v.u;
    unsigned int r = (u + 0x7fffu + ((u >> 16) & 1u)) >> 16;  // RNE
    return (unsigned short)r;
}

__device__ __forceinline__ short4v cvt4(f32x4 a) {
    union { __hip_bfloat162 h[2]; short4v v; } u;
    u.h[0] = __float22bfloat162_rn(float2{a[0], a[1]});
    u.h[1] = __float22bfloat162_rn(float2{a[2], a[3]});
    return u.v;
}

// ---------------- W_en fp32 -> bf16 ----------------
__global__ void wen_convert_kernel(const float* __restrict__ Wen,
                                   unsigned short* __restrict__ Wbf) {
    int idx = blockIdx.x * 256 + threadIdx.x;
    float4 f = ((const float4*)Wen)[idx];
    us4 o = { f2bf(f.x), f2bf(f.y), f2bf(f.z), f2bf(f.w) };
    ((us4*)Wbf)[idx] = o;
}

// ---------------- deproj ----------------
__global__ void deproj_kernel(const float* __restrict__ dehy,
                              const float* __restrict__ Wde,
                              const float* __restrict__ ben,
                              float* __restrict__ dp) {
    int b = blockIdx.x >> 1;
    int h = ((blockIdx.x & 1) << 8) + threadIdx.x;
    const float4* dv = (const float4*)(dehy + (size_t)b * TRG_);
    const float4* wv = (const float4*)(Wde + (size_t)h * TRG_);
    float s = ben[h];
    #pragma unroll 4
    for (int t = 0; t < TRG_ / 4; ++t) {
        float4 a = dv[t], w = wv[t];
        s += a.x * w.x + a.y * w.y + a.z * w.z + a.w * w.w;
    }
    dp[b * TRG_ + h] = s;
}

// ---------------- fused score GEMM + tanh + w_warp reduce + mask ----------------
// R16 (best: 340 us total, absmax 0.0039) with ONE change: epilogue `red`
// scratch UNIONED into Abuf[0] (dead after kt=30 compute(0); all waves past
// the kt=31 MIDBAR barrier before any epilogue write). LDS 42 -> 40 KB ->
// 4 blocks/CU (32 waves, full occupancy; VGPR 64 = 8 waves/SIMD fits).
__global__ __launch_bounds__(512, 4) void score_kernel(
    const float* __restrict__ enhy,
    const unsigned short* __restrict__ Wbf,
    const float* __restrict__ dp,
    const float* __restrict__ past_attn,
    const int* __restrict__ src_mask,
    const float* __restrict__ w_cv,
    const float* __restrict__ w_warp,
    float* __restrict__ out_ee)
{
    __shared__ unsigned short Bbuf[512 * 32];      // 32 KB (single buffer)
    __shared__ unsigned short Abuf[2][64 * 32];    // 8 KB; [0] doubles as `red` in epilogue

    const int tid  = threadIdx.x;
    const int lane = tid & 63;
    const int w    = tid >> 6;       // 0..7 (n-slice)
    const int lj   = lane & 15;
    const int lg   = lane >> 4;
    const int m0   = blockIdx.x * 64;    // flat row into [B*S]
    const int b    = m0 >> 11;

    const int kx = ((lg ^ ((lj >> 1) & 3)) << 4);

    f32x4 acc[4][4];
    const f32x4 fz = {0.f, 0.f, 0.f, 0.f};
    #pragma unroll
    for (int i = 0; i < 4; ++i)
        #pragma unroll
        for (int j = 0; j < 4; ++j) acc[i][j] = fz;

    const int arow = tid >> 3;
    const int akq  = tid & 7;
    const float* aSrc = enhy + (size_t)(m0 + arow) * K_ + (akq << 2);
    const int aDstByte = arow * 64 + (((akq >> 1) ^ ((arow >> 1) & 3)) << 4) + ((akq & 1) << 3);

    const int brow0 = tid >> 2;
    const int bkc0  = tid & 3;
    const unsigned short* bSrc0 = Wbf + (size_t)brow0 * K_ + ((bkc0 ^ ((brow0 >> 1) & 3)) << 3);
    const int bDst0 = w * 1024;

#define SB0() __builtin_amdgcn_sched_barrier(0);
#define LOADA(R, kt) { R = __builtin_nontemporal_load((const f32x4*)(aSrc + ((kt) << 5))); }
#define WRITEA(sel, R) { \
    *(short4v*)((char*)&Abuf[0][0] + (sel) * 4096 + aDstByte) = cvt4(R); }
#define STAGEB(kt) { \
    _Pragma("unroll") \
    for (int j_ = 0; j_ < 4; ++j_) { \
        __builtin_amdgcn_global_load_lds( \
            (const __attribute__((address_space(1))) void*)(bSrc0 + (size_t)j_ * 128 * K_ + ((kt) << 5)), \
            (__attribute__((address_space(3))) void*)((char*)&Bbuf[0] + bDst0 + j_ * 8192), \
            16, 0, 0); \
    } }
#define MIDBAR(N) \
    asm volatile("s_waitcnt vmcnt(" #N ") lgkmcnt(0)" ::: "memory"); \
    SB0() __builtin_amdgcn_s_barrier(); SB0()
#define ENDBAR() \
    asm volatile("s_waitcnt lgkmcnt(0)" ::: "memory"); \
    SB0() __builtin_amdgcn_s_barrier(); SB0()

    auto compute = [&](int sel) {
        const char* Bbase = (const char*)&Bbuf[0];
        const char* Abase = (const char*)&Abuf[0][0] + sel * 4096;
        short8 bfr[4];
        #pragma unroll
        for (int fn = 0; fn < 4; ++fn) {
            int r = (w << 6) + (fn << 4) + lj;
            bfr[fn] = *(const short8*)(Bbase + r * 64 + kx);
        }
        #pragma unroll
        for (int fm = 0; fm < 4; ++fm) {
            int rA = (fm << 4) + lj;
            short8 af = *(const short8*)(Abase + rA * 64 + kx);
            #pragma unroll
            for (int fn = 0; fn < 4; ++fn)
                acc[fm][fn] = __builtin_amdgcn_mfma_f32_16x16x32_bf16(af, bfr[fn], acc[fm][fn], 0, 0, 0);
        }
    };

    // ---- prologue: A(0),A(1) in regs; A(0) -> Abuf[0] ----
    f32x4 aR0, aR1;
    LOADA(aR0, 0);
    LOADA(aR1, 1);
    WRITEA(0, aR0);                 // auto-waits A(0)
    SB0()

    // ---- main loop: kt = 0..29 (unrolled x2 for static reg parity) ----
    for (int kt2 = 0; kt2 < 30; kt2 += 2) {
        // kt even: compute Abuf[0]; write A(kt+1)->Abuf[1]; load A(kt+2)->aR0
        STAGEB(kt2) SB0()
        WRITEA(1, aR1); SB0()       // auto-wait drains A(kt+1) load only
        LOADA(aR0, kt2 + 2); SB0()  // issued LAST -> the 1 left flying
        MIDBAR(1)
        compute(0);
        ENDBAR()
        // kt odd
        STAGEB(kt2 + 1) SB0()
        WRITEA(0, aR0); SB0()
        LOADA(aR1, kt2 + 3); SB0()
        MIDBAR(1)
        compute(1);
        ENDBAR()
    }
    // kt = 30
    STAGEB(30) SB0()
    WRITEA(1, aR1); SB0()           // A(31)
    MIDBAR(0)
    compute(0);
    ENDBAR()
    // kt = 31
    STAGEB(31) SB0()
    MIDBAR(0)
    compute(1);

#undef SB0
#undef LOADA
#undef WRITEA
#undef STAGEB
#undef MIDBAR
#undef ENDBAR

    // ---- epilogue: v = acc + dep + pa*wcv; tanh; *w_warp; reduce over h ----
    // `red` aliases Abuf[0] (bytes 0..2047): Abuf[0]'s last reader was
    // compute(0)@kt=30, and all waves crossed the kt=31 barrier before here.
    float* red = reinterpret_cast<float*>(&Abuf[0][0]);   // [8][64]
    float dep4[4], wcv4[4], wwp4[4];
    #pragma unroll
    for (int fn = 0; fn < 4; ++fn) {
        int h = (w << 6) + (fn << 4) + lj;
        dep4[fn] = dp[b * TRG_ + h];
        wcv4[fn] = w_cv[h];
        wwp4[fn] = w_warp[h];
    }
    #pragma unroll
    for (int fm = 0; fm < 4; ++fm) {
        #pragma unroll
        for (int reg = 0; reg < 4; ++reg) {
            int row = (fm << 4) + (lg << 2) + reg;       // 0..63
            float pa = past_attn[m0 + row];
            float p = 0.f;
            #pragma unroll
            for (int fn = 0; fn < 4; ++fn) {
                float v = acc[fm][fn][reg] + dep4[fn] + pa * wcv4[fn];
                float e = __expf(2.f * v);                       // tanh = 1 - 2/(e^{2v}+1)
                float t = 1.f - 2.f * __builtin_amdgcn_rcpf(e + 1.f);
                p += t * wwp4[fn];
            }
            p += __shfl_xor(p, 1);
            p += __shfl_xor(p, 2);
            p += __shfl_xor(p, 4);
            p += __shfl_xor(p, 8);
            if (lj == 0) red[(w << 6) + row] = p;
        }
    }
    __syncthreads();
    if (tid < 64) {
        float ee = 0.f;
        #pragma unroll
        for (int ww = 0; ww < 8; ++ww) ee += red[(ww << 6) + tid];
        int msk = src_mask[m0 + tid];
        if (msk == 0) ee = -1e20f;
        out_ee[m0 + tid] = ee;
    }
}

// ---------------- row stats: per-row softmax max + 1/sum ----------------
__global__ void rowstat_kernel(const float* __restrict__ ee, float2* __restrict__ mxinv) {
    int b = blockIdx.x, tid = threadIdx.x;   // 64 blocks x 256 threads
    const float* row = ee + (size_t)b * S_;
    float v[8]; float mx = -3.0e38f;
    #pragma unroll
    for (int i = 0; i < 8; ++i) { v[i] = row[tid + (i << 8)]; mx = fmaxf(mx, v[i]); }
    #pragma unroll
    for (int off = 32; off > 0; off >>= 1) mx = fmaxf(mx, __shfl_xor(mx, off));
    __shared__ float sred[4];
    int w = tid >> 6, lane = tid & 63;
    if (lane == 0) sred[w] = mx;
    __syncthreads();
    mx = fmaxf(fmaxf(sred[0], sred[1]), fmaxf(sred[2], sred[3]));
    float sum = 0.f;
    #pragma unroll
    for (int i = 0; i < 8; ++i) sum += __expf(v[i] - mx);
    #pragma unroll
    for (int off = 32; off > 0; off >>= 1) sum += __shfl_xor(sum, off);
    __syncthreads();
    if (lane == 0) sred[w] = sum;
    __syncthreads();
    sum = sred[0] + sred[1] + sred[2] + sred[3];
    if (tid == 0) mxinv[b] = float2{mx, 1.f / sum};
}

// ---------------- context partial + inline attn compute/write ----------------
__global__ void ctx_partial_kernel(const float* __restrict__ ee,
                                   const float2* __restrict__ mxinv,
                                   const float* __restrict__ enhy,
                                   float* __restrict__ attn,
                                   float* __restrict__ part) {
    __shared__ float a_sh[64];
    int bx = blockIdx.x;
    int b = bx >> 5, sc = bx & 31;
    int tid = threadIdx.x;               // 256
    float2 mi = mxinv[b];
    if (tid < 64) {
        float a = __expf(ee[(size_t)b * S_ + sc * 64 + tid] - mi.x) * mi.y;
        a_sh[tid] = a;
        attn[(size_t)b * S_ + sc * 64 + tid] = a;   // each attn elem written once
    }
    __syncthreads();
    const float4* e4 = (const float4*)(enhy + ((size_t)b * S_ + sc * 64) * K_);
    float4 acc = {0.f, 0.f, 0.f, 0.f};
    #pragma unroll 8
    for (int s = 0; s < 64; ++s) {
        float a = a_sh[s];
        float4 ev = e4[(size_t)s * 256 + tid];
        acc.x += a * ev.x; acc.y += a * ev.y; acc.z += a * ev.z; acc.w += a * ev.w;
    }
    ((float4*)part)[(size_t)(sc * 64 + b) * 256 + tid] = acc;
}

__global__ void ctx_reduce_kernel(const float* __restrict__ part, float* __restrict__ outc) {
    int idx = blockIdx.x * 256 + threadIdx.x;
    int b = idx >> 10, d = idx & 1023;
    float s = 0.f;
    #pragma unroll
    for (int sc = 0; sc < 32; ++sc) s += part[(size_t)((sc << 6) + b) * 1024 + d];
    outc[idx] = s;
}

extern "C" void kernel_launch(void* const* d_in, const int* in_sizes, int n_in,
                              void* d_out, int out_size, void* d_ws, size_t ws_size,
                              hipStream_t stream) {
    (void)in_sizes; (void)n_in; (void)out_size; (void)ws_size;

    const float* dehy = (const float*)d_in[0];
    const float* enhy = (const float*)d_in[1];
    const float* past = (const float*)d_in[2];
    const int*   mask = (const int*)d_in[3];
    const float* Wen  = (const float*)d_in[4];
    const float* ben  = (const float*)d_in[5];
    const float* Wde  = (const float*)d_in[6];
    const float* wcv  = (const float*)d_in[7];
    const float* wwp  = (const float*)d_in[8];

    float* out      = (float*)d_out;
    float* out_c    = out;                      // 64*1024
    float* out_attn = out + 65536;              // 64*2048
    float* out_ee   = out + 65536 + 131072;     // 64*2048

    char* ws = (char*)d_ws;
    unsigned short* Wbf = (unsigned short*)ws;               // 1 MB
    float* dp    = (float*)(ws + (1 << 20));                 // 128 KB
    float* part  = (float*)(ws + (1 << 20) + (1 << 17));     // 8 MB
    float2* mxiv = (float2*)(ws + (size_t)10 * (1 << 20));   // 512 B

    wen_convert_kernel<<<512, 256, 0, stream>>>(Wen, Wbf);
    deproj_kernel<<<128, 256, 0, stream>>>(dehy, Wde, ben, dp);
    score_kernel<<<2048, 512, 0, stream>>>(enhy, Wbf, dp, past, mask, wcv, wwp, out_ee);
    rowstat_kernel<<<64, 256, 0, stream>>>(out_ee, mxiv);
    ctx_partial_kernel<<<2048, 256, 0, stream>>>(out_ee, mxiv, enhy, out_attn, part);
    ctx_reduce_kernel<<<256, 256, 0, stream>>>(part, out_c);
}